// Round 1
// 1096.952 us; speedup vs baseline: 1.9600x; 1.9600x over previous
//
#include <hip/hip_runtime.h>
#include <math.h>

#define S_LEN 2048
#define HID_N 4096
#define NH 32
#define NKV 8
#define HD 128
#define INIT_N 128
#define RECENT_N 512
#define HEAVY_N 512
#define SCALE_QK 0.08838834764831845f

typedef __attribute__((ext_vector_type(8))) short short8;
typedef __attribute__((ext_vector_type(4))) float float4v;

__device__ __forceinline__ unsigned short f2bf(float f) {
  unsigned u = __float_as_uint(f);
  unsigned r = (u + 0x7FFFu + ((u >> 16) & 1u)) >> 16;  // RNE (inputs finite)
  return (unsigned short)r;
}

__device__ __forceinline__ float bf2f(unsigned u) { return __uint_as_float(u << 16); }

__device__ __forceinline__ unsigned fkey16(unsigned u) {
  return (u & 0x8000u) ? ((~u) & 0xFFFFu) : (u | 0x8000u);
}

__device__ __forceinline__ void gld_lds16(const unsigned short* g, unsigned short* l) {
  __builtin_amdgcn_global_load_lds(
      (const __attribute__((address_space(1))) unsigned int*)g,
      (__attribute__((address_space(3))) unsigned int*)l, 16, 0, 0);
}

// ---------------- elementwise cast fp32 -> bf16, 8 per thread ----------------
__global__ __launch_bounds__(256) void cast_bf16x8(const float* __restrict__ x,
                                                   unsigned short* __restrict__ y, int n) {
  int i = (blockIdx.x * 256 + threadIdx.x) << 3;
  if (i >= n) return;
  float4 a = *(const float4*)(x + i);
  float4 b = *(const float4*)(x + i + 4);
  union { unsigned short u[8]; short8 v; } o;
  o.u[0] = f2bf(a.x); o.u[1] = f2bf(a.y); o.u[2] = f2bf(a.z); o.u[3] = f2bf(a.w);
  o.u[4] = f2bf(b.x); o.u[5] = f2bf(b.y); o.u[6] = f2bf(b.z); o.u[7] = f2bf(b.w);
  *(short8*)(y + i) = o.v;
}

// ---------------- transpose + cast: w[R][C] fp32 -> wt[C][R] bf16 ------------
__global__ __launch_bounds__(256) void transpose_cast(const float* __restrict__ w,
                                                      unsigned short* __restrict__ wt,
                                                      int R, int C) {
  __shared__ unsigned short t[64][65];
  const int c0 = blockIdx.x * 64;
  const int r0 = blockIdx.y * 64;
  const int tx = threadIdx.x & 63;
  const int ty = threadIdx.x >> 6;
#pragma unroll
  for (int i = 0; i < 16; ++i)
    t[ty + 4 * i][tx] = f2bf(w[(size_t)(r0 + ty + 4 * i) * C + c0 + tx]);
  __syncthreads();
#pragma unroll
  for (int i = 0; i < 16; ++i)
    wt[(size_t)(c0 + ty + 4 * i) * R + r0 + tx] = t[tx][ty + 4 * i];
}

// ---------------- bf16 MFMA GEMM (m97 pattern): C = A[M][K] @ BT[N][K]^T -----
__global__ __launch_bounds__(256) void gemm_bf16(const unsigned short* __restrict__ A,
                                                 const unsigned short* __restrict__ BT,
                                                 float* __restrict__ C,
                                                 int M, int N, int K) {
  __shared__ __align__(16) unsigned short As[128 * 32];
  __shared__ __align__(16) unsigned short Bs[128 * 32];
  const int tid = threadIdx.x;
  const int lane = tid & 63;
  const int wid = tid >> 6;
  const int m0 = blockIdx.y * 128;
  const int n0 = blockIdx.x * 128;
  const int wm = (wid & 1) * 64;
  const int wn = (wid >> 1) * 64;
  const int col = lane & 15;
  const int quad = lane >> 4;

  float4v acc[4][4] = {};

  const int crow = tid >> 2;
  const int ckc = (tid & 3) << 3;

  for (int k0 = 0; k0 < K; k0 += 32) {
#pragma unroll
    for (int i = 0; i < 2; ++i) {
      const int row = i * 64 + crow;
      unsigned short* la = &As[(i * 256 + wid * 64) << 3];
      unsigned short* lb = &Bs[(i * 256 + wid * 64) << 3];
      gld_lds16(A + (size_t)(m0 + row) * K + k0 + ckc, la);
      gld_lds16(BT + (size_t)(n0 + row) * K + k0 + ckc, lb);
    }
    __syncthreads();

    short8 af[4], bf[4];
#pragma unroll
    for (int i = 0; i < 4; ++i) {
      af[i] = *(const short8*)&As[((wm + 16 * i + col) << 5) + (quad << 3)];
      bf[i] = *(const short8*)&Bs[((wn + 16 * i + col) << 5) + (quad << 3)];
    }
#pragma unroll
    for (int i = 0; i < 4; ++i)
#pragma unroll
      for (int j = 0; j < 4; ++j)
        acc[i][j] = __builtin_amdgcn_mfma_f32_16x16x32_bf16(af[i], bf[j], acc[i][j], 0, 0, 0);
    __syncthreads();
  }

#pragma unroll
  for (int i = 0; i < 4; ++i)
#pragma unroll
    for (int j = 0; j < 4; ++j) {
      size_t base = (size_t)(m0 + wm + 16 * i + quad * 4) * N + n0 + wn + 16 * j + col;
      C[base] = acc[i][j][0];
      C[base + N] = acc[i][j][1];
      C[base + 2 * (size_t)N] = acc[i][j][2];
      C[base + 3 * (size_t)N] = acc[i][j][3];
    }
}

// ---------------- RoPE + cast to bf16: x[S][nheads*HD] fp32 -> y bf16 --------
__global__ __launch_bounds__(256) void rope_cast(const float* __restrict__ x,
                                                 unsigned short* __restrict__ y, int nheads) {
  int idx = blockIdx.x * 256 + threadIdx.x;
  int i = idx & 63;
  int rest = idx >> 6;
  int hh = rest % nheads;
  int s = rest / nheads;
  if (s >= S_LEN) return;
  const float* p = x + ((size_t)s * nheads + hh) * HD;
  unsigned short* o = y + ((size_t)s * nheads + hh) * HD;
  float inv = (float)(1.0 / pow(10000.0, (double)(2 * i) / 128.0));
  float ang = (float)s * inv;
  float c = cosf(ang);
  float sn = sinf(ang);
  float x1 = p[i];
  float x2 = p[i + 64];
  o[i] = f2bf(x1 * c - x2 * sn);
  o[i + 64] = f2bf(x2 * c + x1 * sn);
}

// ---------------- fused heavy-hitter attention, MFMA, 16 q-rows/block --------
// qb: bf16 [S][NH*HD] (RoPE'd), kb: bf16 [S][NKV*HD] (RoPE'd),
// vt: bf16 [NKV*HD][S] (V transposed), ao: fp32 [S][NH*HD].
// Scores live in LDS as bf16, XOR-swizzled: idx(q,k) = (q*2048 + k) ^ ((q&7)<<3).
__global__ __launch_bounds__(256, 2) void attn_mfma(const unsigned short* __restrict__ qb,
                                                    const unsigned short* __restrict__ kb,
                                                    const unsigned short* __restrict__ vt,
                                                    float* __restrict__ ao) {
  const int qi0 = blockIdx.x << 4;
  const int h = blockIdx.y;
  const int g = h >> 2;
  const int tid = threadIdx.x;
  const int lane = tid & 63;
  const int wid = tid >> 6;
  const int col = lane & 15;
  const int quad = lane >> 4;
  const int nkm = qi0 + 16;
  const int nkm32 = (nkm + 31) & ~31;

  __shared__ __align__(16) unsigned short sc[16 * 2048];
  __shared__ float sumv[16];

  // ---- Phase A: S = (Q K^T) * scale via MFMA; K frags streamed from L2 ----
  short8 qf[4];
  {
    const unsigned short* qrow = qb + (size_t)(qi0 + col) * (NH * HD) + h * HD + (quad << 3);
#pragma unroll
    for (int dt = 0; dt < 4; ++dt) qf[dt] = *(const short8*)(qrow + dt * 32);
  }
  const int ntiles = nkm >> 4;
  for (int t = wid; t < ntiles; t += 4) {
    const int k0 = t << 4;
    const unsigned short* krow = kb + (size_t)(k0 + col) * (NKV * HD) + g * HD + (quad << 3);
    float4v acc = {};
#pragma unroll
    for (int dt = 0; dt < 4; ++dt) {
      short8 kf = *(const short8*)(krow + dt * 32);
      acc = __builtin_amdgcn_mfma_f32_16x16x32_bf16(qf[dt], kf, acc, 0, 0, 0);
    }
    // C layout: q-row = quad*4 + reg, k-col = lane&15
#pragma unroll
    for (int r = 0; r < 4; ++r) {
      int q = (quad << 2) + r;
      sc[(q * 2048 + k0 + col) ^ ((q & 7) << 3)] = f2bf(acc[r] * SCALE_QK);
    }
  }
  __syncthreads();

  // ---- Phase B: per-row top-k threshold + softmax (wave w owns rows 4w..4w+3) ----
  const unsigned long long lmlt = (1ull << lane) - 1ull;
  for (int rr = 0; rr < 4; ++rr) {
    const int r = (wid << 2) + rr;
    const int qi = qi0 + r;
    const int mhi = qi - RECENT_N;       // last middle index
    const int m = mhi - INIT_N + 1;      // middle count
    const bool need = (m > HEAVY_N);
    const unsigned swz = (r & 7) << 3;
    const int rbase = r * 2048;

    unsigned T = 0, rem = 0;
    if (need) {
      // 16-bit radix select over bf16 score keys; pads (0) never match target.
      unsigned myk[22];
#pragma unroll
      for (int j = 0; j < 11; ++j) {
        int off = (lane + (j << 6)) << 1;  // 0..1406 step 2, covers m <= 1408
        unsigned u = *(const unsigned*)&sc[(rbase + INIT_N + off) ^ swz];
        unsigned f0 = fkey16(u & 0xFFFFu);
        unsigned f1 = fkey16(u >> 16);
        myk[2 * j] = (off < m) ? f0 : 0u;
        myk[2 * j + 1] = (off + 1 < m) ? f1 : 0u;
      }
      unsigned prefix = 0, rm = HEAVY_N;
#pragma unroll 1
      for (int bit = 15; bit >= 0; --bit) {
        unsigned target = (prefix >> bit) | 1u;
        unsigned cnt = 0;
#pragma unroll
        for (int j = 0; j < 22; ++j)
          cnt += (unsigned)__popcll(__ballot((myk[j] >> bit) == target));
        if (cnt >= rm) prefix |= (1u << bit);
        else rm -= cnt;
      }
      T = prefix;
      rem = rm;
    }

    // Max over causal range only: the causal max is always in the selected set
    // (init/recent are always kept; a middle max is the #1 heavy hitter).
    float mx = -3.402823466e38f;
#pragma unroll 1
    for (int c0 = 0; c0 <= qi; c0 += 128) {
      int k2 = c0 + (lane << 1);
      unsigned u = *(const unsigned*)&sc[(rbase + k2) ^ swz];
      float s0 = bf2f(u & 0xFFFFu);
      float s1 = bf2f(u >> 16);
      if (k2 <= qi) mx = fmaxf(mx, s0);
      if (k2 + 1 <= qi) mx = fmaxf(mx, s1);
    }
#pragma unroll
    for (int off = 32; off; off >>= 1) mx = fmaxf(mx, __shfl_xor(mx, off, 64));

    float sum = 0.f;
    unsigned cum = 0;
#pragma unroll 1
    for (int c0 = 0; c0 < nkm32; c0 += 128) {
      int k2 = c0 + (lane << 1);
      int idx = (rbase + k2) ^ swz;
      unsigned u = *(const unsigned*)&sc[idx];
      bool ic0 = k2 <= qi, ic1 = (k2 + 1) <= qi;
      bool sel0, sel1;
      if (!need) {
        sel0 = ic0;
        sel1 = ic1;
      } else {
        bool mid0 = ic0 && (k2 >= INIT_N) && (k2 <= mhi);
        bool mid1 = ic1 && (k2 + 1 >= INIT_N) && (k2 + 1 <= mhi);
        unsigned f0 = fkey16(u & 0xFFFFu);
        unsigned f1 = fkey16(u >> 16);
        unsigned long long eq0 = __ballot(mid0 && (f0 == T));
        unsigned long long eq1 = __ballot(mid1 && (f1 == T));
        unsigned pre0 = cum + (unsigned)__popcll(eq0 & lmlt) + (unsigned)__popcll(eq1 & lmlt);
        unsigned pre1 = pre0 + (unsigned)((eq0 >> lane) & 1ull);
        sel0 = ic0 && (!mid0 || (f0 > T) || ((f0 == T) && (pre0 < rem)));
        sel1 = ic1 && (!mid1 || (f1 > T) || ((f1 == T) && (pre1 < rem)));
        cum += (unsigned)__popcll(eq0) + (unsigned)__popcll(eq1);
      }
      float e0 = sel0 ? __expf(bf2f(u & 0xFFFFu) - mx) : 0.f;
      float e1 = sel1 ? __expf(bf2f(u >> 16) - mx) : 0.f;
      sum += e0 + e1;
      *(unsigned*)&sc[idx] = (unsigned)f2bf(e0) | ((unsigned)f2bf(e1) << 16);
    }
#pragma unroll
    for (int off = 32; off; off >>= 1) sum += __shfl_xor(sum, off, 64);
    if (lane == 0) sumv[r] = sum;
  }
  __syncthreads();

  // ---- Phase C: O = P V via MFMA; wave w owns d-slice [32w, 32w+32) ----
  float4v a0 = {}, a1 = {};
  const int db = wid << 5;
  const unsigned short* vrow0 = vt + (size_t)(g * HD + db + col) * S_LEN + (quad << 3);
  const unsigned short* vrow1 = vrow0 + (size_t)16 * S_LEN;
  const unsigned pswz = (unsigned)((col & 7) << 3);
#pragma unroll 1
  for (int k0 = 0; k0 < nkm32; k0 += 32) {
    short8 pf = *(const short8*)&sc[(col * 2048 + k0 + (quad << 3)) ^ pswz];
    short8 v0 = *(const short8*)(vrow0 + k0);
    short8 v1 = *(const short8*)(vrow1 + k0);
    a0 = __builtin_amdgcn_mfma_f32_16x16x32_bf16(pf, v0, a0, 0, 0, 0);
    a1 = __builtin_amdgcn_mfma_f32_16x16x32_bf16(pf, v1, a1, 0, 0, 0);
  }
#pragma unroll
  for (int r = 0; r < 4; ++r) {
    int qq = (quad << 2) + r;
    float inv = 1.0f / sumv[qq];
    size_t o = (size_t)(qi0 + qq) * (NH * HD) + h * HD + db;
    ao[o + col] = a0[r] * inv;
    ao[o + 16 + col] = a1[r] * inv;
  }
}

// ---------------------------------------------------------------------------
extern "C" void kernel_launch(void* const* d_in, const int* in_sizes, int n_in,
                              void* d_out, int out_size, void* d_ws, size_t ws_size,
                              hipStream_t stream) {
  const float* hidden = (const float*)d_in[0];
  const float* wq = (const float*)d_in[1];
  const float* wk = (const float*)d_in[2];
  const float* wv = (const float*)d_in[3];
  const float* wo = (const float*)d_in[4];
  float* out = (float*)d_out;

  // workspace layout (floats), 32M floats = 128 MB used:
  //  [ 0M, 8M)  q fp32 [S][NH*HD]          -> reused as ao fp32 after rope_cast_q
  //  [ 8M,10M)  kbuf fp32 [S][NKV*HD]
  //  [10M,12M)  vbuf fp32 [S][NKV*HD]
  //  [12M,16M)  qb16 bf16 [S][NH*HD]
  //  [16M,20M)  hb bf16 [S][HID]           -> reused as aob bf16
  //  [20M,28M)  wTb bf16 [4096][4096]      (wq^T, then wo^T)
  //  [28M,30M)  wkT bf16                   -> reused: kb16 (2M ush) + vT16 (2M ush)
  //  [30M,32M)  wvT bf16
  float* ws = (float*)d_ws;
  const size_t M1 = 1024 * 1024;
  float* q = ws;
  float* ao = ws;
  float* kbuf = ws + 8 * M1;
  float* vbuf = ws + 10 * M1;
  unsigned short* qb16 = (unsigned short*)(ws + 12 * M1);
  unsigned short* hb = (unsigned short*)(ws + 16 * M1);
  unsigned short* aob = hb;
  unsigned short* wTb = (unsigned short*)(ws + 20 * M1);
  unsigned short* wkT = (unsigned short*)(ws + 28 * M1);
  unsigned short* wvT = (unsigned short*)(ws + 30 * M1);
  unsigned short* kb16 = wkT;             // [S][NKV*HD] bf16 (after k-gemm done)
  unsigned short* vT16 = wkT + 2 * M1;    // [NKV*HD][S] bf16

  dim3 blk(256);
  const int NE = S_LEN * HID_N;  // 8,388,608

  cast_bf16x8<<<NE / 2048, blk, 0, stream>>>(hidden, hb, NE);
  transpose_cast<<<dim3(HID_N / 64, HID_N / 64), blk, 0, stream>>>(wq, wTb, HID_N, NH * HD);
  transpose_cast<<<dim3((NKV * HD) / 64, HID_N / 64), blk, 0, stream>>>(wk, wkT, HID_N, NKV * HD);
  transpose_cast<<<dim3((NKV * HD) / 64, HID_N / 64), blk, 0, stream>>>(wv, wvT, HID_N, NKV * HD);

  gemm_bf16<<<dim3((NH * HD) / 128, S_LEN / 128), blk, 0, stream>>>(hb, wTb, q, S_LEN, NH * HD, HID_N);
  gemm_bf16<<<dim3((NKV * HD) / 128, S_LEN / 128), blk, 0, stream>>>(hb, wkT, kbuf, S_LEN, NKV * HD, HID_N);
  gemm_bf16<<<dim3((NKV * HD) / 128, S_LEN / 128), blk, 0, stream>>>(hb, wvT, vbuf, S_LEN, NKV * HD, HID_N);

  transpose_cast<<<dim3(HID_N / 64, (NH * HD) / 64), blk, 0, stream>>>(wo, wTb, NH * HD, HID_N);

  rope_cast<<<(S_LEN * NH * 64) / 256, blk, 0, stream>>>(q, qb16, NH);
  rope_cast<<<(S_LEN * NKV * 64) / 256, blk, 0, stream>>>(kbuf, kb16, NKV);
  transpose_cast<<<dim3((NKV * HD) / 64, S_LEN / 64), blk, 0, stream>>>(vbuf, vT16, S_LEN, NKV * HD);

  attn_mfma<<<dim3(S_LEN / 16, NH), blk, 0, stream>>>(qb16, kb16, vT16, ao);

  cast_bf16x8<<<NE / 2048, blk, 0, stream>>>(ao, aob, NE);
  gemm_bf16<<<dim3(HID_N / 128, S_LEN / 128), blk, 0, stream>>>(aob, wTb, out, S_LEN, HID_N, NH * HD);
}

// Round 2
// 941.866 us; speedup vs baseline: 2.2828x; 1.1647x over previous
//
#include <hip/hip_runtime.h>
#include <math.h>

#define S_LEN 2048
#define HID_N 4096
#define NH 32
#define NKV 8
#define HD 128
#define INIT_N 128
#define RECENT_N 512
#define HEAVY_N 512
#define SCALE_QK 0.08838834764831845f

typedef __attribute__((ext_vector_type(8))) short short8;
typedef __attribute__((ext_vector_type(4))) float float4v;

__device__ __forceinline__ unsigned short f2bf(float f) {
  unsigned u = __float_as_uint(f);
  unsigned r = (u + 0x7FFFu + ((u >> 16) & 1u)) >> 16;  // RNE (inputs finite)
  return (unsigned short)r;
}

__device__ __forceinline__ float bf2f(unsigned u) { return __uint_as_float(u << 16); }

__device__ __forceinline__ unsigned fkey16(unsigned u) {
  return (u & 0x8000u) ? ((~u) & 0xFFFFu) : (u | 0x8000u);
}

__device__ __forceinline__ void gld_lds16(const unsigned short* g, unsigned short* l) {
  __builtin_amdgcn_global_load_lds(
      (const __attribute__((address_space(1))) unsigned int*)g,
      (__attribute__((address_space(3))) unsigned int*)l, 16, 0, 0);
}

// ---------------- elementwise cast fp32 -> bf16, 8 per thread ----------------
__global__ __launch_bounds__(256) void cast_bf16x8(const float* __restrict__ x,
                                                   unsigned short* __restrict__ y, int n) {
  int i = (blockIdx.x * 256 + threadIdx.x) << 3;
  if (i >= n) return;
  float4 a = *(const float4*)(x + i);
  float4 b = *(const float4*)(x + i + 4);
  union { unsigned short u[8]; short8 v; } o;
  o.u[0] = f2bf(a.x); o.u[1] = f2bf(a.y); o.u[2] = f2bf(a.z); o.u[3] = f2bf(a.w);
  o.u[4] = f2bf(b.x); o.u[5] = f2bf(b.y); o.u[6] = f2bf(b.z); o.u[7] = f2bf(b.w);
  *(short8*)(y + i) = o.v;
}

// ------------- transpose + cast: w[R][C] (row stride ldw) -> wt[C][R] bf16 ---
__global__ __launch_bounds__(256) void transpose_cast(const float* __restrict__ w,
                                                      unsigned short* __restrict__ wt,
                                                      int R, int C, int ldw) {
  __shared__ unsigned short t[64][65];
  const int c0 = blockIdx.x * 64;
  const int r0 = blockIdx.y * 64;
  const int tx = threadIdx.x & 63;
  const int ty = threadIdx.x >> 6;
#pragma unroll
  for (int i = 0; i < 16; ++i)
    t[ty + 4 * i][tx] = f2bf(w[(size_t)(r0 + ty + 4 * i) * ldw + c0 + tx]);
  __syncthreads();
#pragma unroll
  for (int i = 0; i < 16; ++i)
    wt[(size_t)(c0 + ty + 4 * i) * R + r0 + tx] = t[tx][ty + 4 * i];
}

// ---------------- bf16 MFMA GEMM (m97 pattern): C = A[M][K] @ BT[N][K]^T -----
__global__ __launch_bounds__(256) void gemm_bf16(const unsigned short* __restrict__ A,
                                                 const unsigned short* __restrict__ BT,
                                                 float* __restrict__ C,
                                                 int M, int N, int K) {
  __shared__ __align__(16) unsigned short As[128 * 32];
  __shared__ __align__(16) unsigned short Bs[128 * 32];
  const int tid = threadIdx.x;
  const int lane = tid & 63;
  const int wid = tid >> 6;
  const int m0 = blockIdx.y * 128;
  const int n0 = blockIdx.x * 128;
  const int wm = (wid & 1) * 64;
  const int wn = (wid >> 1) * 64;
  const int col = lane & 15;
  const int quad = lane >> 4;

  float4v acc[4][4] = {};

  const int crow = tid >> 2;
  const int ckc = (tid & 3) << 3;

  for (int k0 = 0; k0 < K; k0 += 32) {
#pragma unroll
    for (int i = 0; i < 2; ++i) {
      const int row = i * 64 + crow;
      unsigned short* la = &As[(i * 256 + wid * 64) << 3];
      unsigned short* lb = &Bs[(i * 256 + wid * 64) << 3];
      gld_lds16(A + (size_t)(m0 + row) * K + k0 + ckc, la);
      gld_lds16(BT + (size_t)(n0 + row) * K + k0 + ckc, lb);
    }
    __syncthreads();

    short8 af[4], bf[4];
#pragma unroll
    for (int i = 0; i < 4; ++i) {
      af[i] = *(const short8*)&As[((wm + 16 * i + col) << 5) + (quad << 3)];
      bf[i] = *(const short8*)&Bs[((wn + 16 * i + col) << 5) + (quad << 3)];
    }
#pragma unroll
    for (int i = 0; i < 4; ++i)
#pragma unroll
      for (int j = 0; j < 4; ++j)
        acc[i][j] = __builtin_amdgcn_mfma_f32_16x16x32_bf16(af[i], bf[j], acc[i][j], 0, 0, 0);
    __syncthreads();
  }

#pragma unroll
  for (int i = 0; i < 4; ++i)
#pragma unroll
    for (int j = 0; j < 4; ++j) {
      size_t base = (size_t)(m0 + wm + 16 * i + quad * 4) * N + n0 + wn + 16 * j + col;
      C[base] = acc[i][j][0];
      C[base + N] = acc[i][j][1];
      C[base + 2 * (size_t)N] = acc[i][j][2];
      C[base + 3 * (size_t)N] = acc[i][j][3];
    }
}

// ------- RoPE + cast to bf16: x[S][*] (stride ldx) -> y (stride ldy) bf16 ----
__global__ __launch_bounds__(256) void rope_cast(const float* __restrict__ x,
                                                 unsigned short* __restrict__ y,
                                                 int nheads, int ldx, int ldy) {
  int idx = blockIdx.x * 256 + threadIdx.x;
  int i = idx & 63;
  int rest = idx >> 6;
  int hh = rest % nheads;
  int s = rest / nheads;
  if (s >= S_LEN) return;
  const float* p = x + (size_t)s * ldx + hh * HD;
  unsigned short* o = y + (size_t)s * ldy + hh * HD;
  float inv = (float)(1.0 / pow(10000.0, (double)(2 * i) / 128.0));
  float ang = (float)s * inv;
  float c = cosf(ang);
  float sn = sinf(ang);
  float x1 = p[i];
  float x2 = p[i + 64];
  o[i] = f2bf(x1 * c - x2 * sn);
  o[i + 64] = f2bf(x2 * c + x1 * sn);
}

// ---------------- fused heavy-hitter attention, MFMA, 16 q-rows/block --------
// qb: bf16 [S][NH*HD] (RoPE'd), kb: bf16 [S][NKV*HD] (RoPE'd),
// vt: bf16 [NKV*HD][S] (V transposed), ao16: bf16 [S][NH*HD].
// Scores in LDS as bf16, XOR-swizzled: idx(q,k) = (q*SMAX + k) ^ ((q&7)<<3).
// SMAX=1024 launch covers qi0 in [0,1024): radix select statically dead
// (m <= 384 < HEAVY), LDS 32KB -> 4 blocks/CU.
template <int SMAX>
__global__ __launch_bounds__(256, SMAX == 1024 ? 4 : 2)
void attn_mfma(const unsigned short* __restrict__ qb,
               const unsigned short* __restrict__ kb,
               const unsigned short* __restrict__ vt,
               unsigned short* __restrict__ ao16, int qbase) {
  const int qi0 = (qbase + blockIdx.x) << 4;
  const int h = blockIdx.y;
  const int g = h >> 2;
  const int tid = threadIdx.x;
  const int lane = tid & 63;
  const int wid = tid >> 6;
  const int col = lane & 15;
  const int quad = lane >> 4;
  const int nkm = qi0 + 16;
  const int nkm32 = (nkm + 31) & ~31;

  __shared__ __align__(16) unsigned short sc[16 * SMAX];
  __shared__ float sumv[16];

  // ---- Phase A: S = (Q K^T) * scale via MFMA, 2 tiles deep ----
  short8 qf[4];
  {
    const unsigned short* qrow = qb + (size_t)(qi0 + col) * (NH * HD) + h * HD + (quad << 3);
#pragma unroll
    for (int dt = 0; dt < 4; ++dt) qf[dt] = *(const short8*)(qrow + dt * 32);
  }
  const int ntiles = nkm >> 4;
  int t = wid;
  for (; t + 4 < ntiles; t += 8) {
    const int k0a = t << 4;
    const int k0b = (t + 4) << 4;
    const unsigned short* kra = kb + (size_t)(k0a + col) * (NKV * HD) + g * HD + (quad << 3);
    const unsigned short* krb = kb + (size_t)(k0b + col) * (NKV * HD) + g * HD + (quad << 3);
    short8 kfa[4], kfb[4];
#pragma unroll
    for (int dt = 0; dt < 4; ++dt) kfa[dt] = *(const short8*)(kra + dt * 32);
#pragma unroll
    for (int dt = 0; dt < 4; ++dt) kfb[dt] = *(const short8*)(krb + dt * 32);
    float4v acca = {}, accb = {};
#pragma unroll
    for (int dt = 0; dt < 4; ++dt) {
      acca = __builtin_amdgcn_mfma_f32_16x16x32_bf16(qf[dt], kfa[dt], acca, 0, 0, 0);
      accb = __builtin_amdgcn_mfma_f32_16x16x32_bf16(qf[dt], kfb[dt], accb, 0, 0, 0);
    }
#pragma unroll
    for (int r = 0; r < 4; ++r) {
      int q = (quad << 2) + r;
      sc[(q * SMAX + k0a + col) ^ ((q & 7) << 3)] = f2bf(acca[r] * SCALE_QK);
      sc[(q * SMAX + k0b + col) ^ ((q & 7) << 3)] = f2bf(accb[r] * SCALE_QK);
    }
  }
  if (t < ntiles) {
    const int k0 = t << 4;
    const unsigned short* krow = kb + (size_t)(k0 + col) * (NKV * HD) + g * HD + (quad << 3);
    float4v acc = {};
#pragma unroll
    for (int dt = 0; dt < 4; ++dt) {
      short8 kf = *(const short8*)(krow + dt * 32);
      acc = __builtin_amdgcn_mfma_f32_16x16x32_bf16(qf[dt], kf, acc, 0, 0, 0);
    }
#pragma unroll
    for (int r = 0; r < 4; ++r) {
      int q = (quad << 2) + r;
      sc[(q * SMAX + k0 + col) ^ ((q & 7) << 3)] = f2bf(acc[r] * SCALE_QK);
    }
  }
  __syncthreads();

  // ---- Phase B: per-row top-k threshold + softmax (wave w owns rows 4w..4w+3) ----
  const unsigned long long lmlt = (1ull << lane) - 1ull;
  for (int rr = 0; rr < 4; ++rr) {
    const int r = (wid << 2) + rr;
    const int qi = qi0 + r;
    const int mhi = qi - RECENT_N;       // last middle index
    const int m = mhi - INIT_N + 1;      // middle count
    const bool need = (SMAX > 1024) && (m > HEAVY_N);
    const unsigned swz = (r & 7) << 3;
    const int rbase = r * SMAX;

    unsigned T = 0, rem = 0;
    if (need) {
      // 16-bit radix select over bf16 score keys; pads (0) never match target.
      unsigned myk[22];
#pragma unroll
      for (int j = 0; j < 11; ++j) {
        int off = (lane + (j << 6)) << 1;  // 0..1406 step 2, covers m <= 1408
        unsigned u = *(const unsigned*)&sc[(rbase + INIT_N + off) ^ swz];
        unsigned f0 = fkey16(u & 0xFFFFu);
        unsigned f1 = fkey16(u >> 16);
        myk[2 * j] = (off < m) ? f0 : 0u;
        myk[2 * j + 1] = (off + 1 < m) ? f1 : 0u;
      }
      unsigned prefix = 0, rm = HEAVY_N;
#pragma unroll 1
      for (int bit = 15; bit >= 0; --bit) {
        unsigned target = (prefix >> bit) | 1u;
        unsigned cnt = 0;
#pragma unroll
        for (int j = 0; j < 22; ++j)
          cnt += (unsigned)__popcll(__ballot((myk[j] >> bit) == target));
        if (cnt >= rm) prefix |= (1u << bit);
        else rm -= cnt;
      }
      T = prefix;
      rem = rm;
    }

    // Max over causal range only: the causal max is always in the selected set.
    float mx = -3.402823466e38f;
#pragma unroll 1
    for (int c0 = 0; c0 <= qi; c0 += 128) {
      int k2 = c0 + (lane << 1);
      unsigned u = *(const unsigned*)&sc[(rbase + k2) ^ swz];
      float s0 = bf2f(u & 0xFFFFu);
      float s1 = bf2f(u >> 16);
      if (k2 <= qi) mx = fmaxf(mx, s0);
      if (k2 + 1 <= qi) mx = fmaxf(mx, s1);
    }
#pragma unroll
    for (int off = 32; off; off >>= 1) mx = fmaxf(mx, __shfl_xor(mx, off, 64));

    float sum = 0.f;
    unsigned cum = 0;
#pragma unroll 1
    for (int c0 = 0; c0 < nkm32; c0 += 128) {
      int k2 = c0 + (lane << 1);
      int idx = (rbase + k2) ^ swz;
      unsigned u = *(const unsigned*)&sc[idx];
      bool ic0 = k2 <= qi, ic1 = (k2 + 1) <= qi;
      bool sel0, sel1;
      if (!need) {
        sel0 = ic0;
        sel1 = ic1;
      } else {
        bool mid0 = ic0 && (k2 >= INIT_N) && (k2 <= mhi);
        bool mid1 = ic1 && (k2 + 1 >= INIT_N) && (k2 + 1 <= mhi);
        unsigned f0 = fkey16(u & 0xFFFFu);
        unsigned f1 = fkey16(u >> 16);
        unsigned long long eq0 = __ballot(mid0 && (f0 == T));
        unsigned long long eq1 = __ballot(mid1 && (f1 == T));
        unsigned pre0 = cum + (unsigned)__popcll(eq0 & lmlt) + (unsigned)__popcll(eq1 & lmlt);
        unsigned pre1 = pre0 + (unsigned)((eq0 >> lane) & 1ull);
        sel0 = ic0 && (!mid0 || (f0 > T) || ((f0 == T) && (pre0 < rem)));
        sel1 = ic1 && (!mid1 || (f1 > T) || ((f1 == T) && (pre1 < rem)));
        cum += (unsigned)__popcll(eq0) + (unsigned)__popcll(eq1);
      }
      float e0 = sel0 ? __expf(bf2f(u & 0xFFFFu) - mx) : 0.f;
      float e1 = sel1 ? __expf(bf2f(u >> 16) - mx) : 0.f;
      sum += e0 + e1;
      *(unsigned*)&sc[idx] = (unsigned)f2bf(e0) | ((unsigned)f2bf(e1) << 16);
    }
#pragma unroll
    for (int off = 32; off; off >>= 1) sum += __shfl_xor(sum, off, 64);
    if (lane == 0) sumv[r] = sum;
  }
  __syncthreads();

  // ---- Phase C: O = P V via MFMA, 2 steps deep, 4 independent accumulators --
  float4v a0 = {}, a1 = {}, b0 = {}, b1 = {};
  const int db = wid << 5;
  const unsigned short* vrow0 = vt + (size_t)(g * HD + db + col) * S_LEN + (quad << 3);
  const unsigned short* vrow1 = vrow0 + (size_t)16 * S_LEN;
  const unsigned pswz = (unsigned)((col & 7) << 3);
  int k0 = 0;
  for (; k0 + 32 < nkm32; k0 += 64) {
    short8 pf0 = *(const short8*)&sc[(col * SMAX + k0 + (quad << 3)) ^ pswz];
    short8 pf1 = *(const short8*)&sc[(col * SMAX + k0 + 32 + (quad << 3)) ^ pswz];
    short8 v00 = *(const short8*)(vrow0 + k0);
    short8 v01 = *(const short8*)(vrow1 + k0);
    short8 v10 = *(const short8*)(vrow0 + k0 + 32);
    short8 v11 = *(const short8*)(vrow1 + k0 + 32);
    a0 = __builtin_amdgcn_mfma_f32_16x16x32_bf16(pf0, v00, a0, 0, 0, 0);
    a1 = __builtin_amdgcn_mfma_f32_16x16x32_bf16(pf0, v01, a1, 0, 0, 0);
    b0 = __builtin_amdgcn_mfma_f32_16x16x32_bf16(pf1, v10, b0, 0, 0, 0);
    b1 = __builtin_amdgcn_mfma_f32_16x16x32_bf16(pf1, v11, b1, 0, 0, 0);
  }
  if (k0 < nkm32) {
    short8 pf = *(const short8*)&sc[(col * SMAX + k0 + (quad << 3)) ^ pswz];
    short8 v0 = *(const short8*)(vrow0 + k0);
    short8 v1 = *(const short8*)(vrow1 + k0);
    a0 = __builtin_amdgcn_mfma_f32_16x16x32_bf16(pf, v0, a0, 0, 0, 0);
    a1 = __builtin_amdgcn_mfma_f32_16x16x32_bf16(pf, v1, a1, 0, 0, 0);
  }
  a0 += b0;
  a1 += b1;
#pragma unroll
  for (int r = 0; r < 4; ++r) {
    int qq = (quad << 2) + r;
    float inv = 1.0f / sumv[qq];
    size_t o = (size_t)(qi0 + qq) * (NH * HD) + h * HD + db;
    ao16[o + col] = f2bf(a0[r] * inv);
    ao16[o + 16 + col] = f2bf(a1[r] * inv);
  }
}

// ---------------------------------------------------------------------------
extern "C" void kernel_launch(void* const* d_in, const int* in_sizes, int n_in,
                              void* d_out, int out_size, void* d_ws, size_t ws_size,
                              hipStream_t stream) {
  const float* hidden = (const float*)d_in[0];
  const float* wq = (const float*)d_in[1];
  const float* wk = (const float*)d_in[2];
  const float* wv = (const float*)d_in[3];
  const float* wo = (const float*)d_in[4];
  float* out = (float*)d_out;

  // workspace layout (floats), 30M floats = 120 MB used:
  //  [ 0M,12M)  qkv f32 [S][6144] (q | k | v)
  //  [12M,16M)  qb16 bf16 [S][NH*HD]
  //  [16M,20M)  hb bf16 [S][HID]           -> reused as aob bf16
  //  [20M,32M)  wqkvT bf16 [6144][4096]    -> after QKV gemm reused:
  //               [20M,28M) woT bf16 [4096][4096]
  //               [28M,29M) kb16 bf16 [S][NKV*HD]
  //               [29M,30M) vT16 bf16 [NKV*HD][S]
  float* ws = (float*)d_ws;
  const size_t M1 = 1024 * 1024;
  float* qkv = ws;
  unsigned short* qb16 = (unsigned short*)(ws + 12 * M1);
  unsigned short* hb = (unsigned short*)(ws + 16 * M1);
  unsigned short* aob = hb;
  unsigned short* wqkvT = (unsigned short*)(ws + 20 * M1);
  unsigned short* woT = wqkvT;
  unsigned short* kb16 = (unsigned short*)(ws + 28 * M1);
  unsigned short* vT16 = (unsigned short*)(ws + 29 * M1);

  dim3 blk(256);
  const int NE = S_LEN * HID_N;  // 8,388,608

  cast_bf16x8<<<NE / 2048, blk, 0, stream>>>(hidden, hb, NE);
  transpose_cast<<<dim3(HID_N / 64, HID_N / 64), blk, 0, stream>>>(wq, wqkvT, HID_N, HID_N, HID_N);
  transpose_cast<<<dim3((NKV * HD) / 64, HID_N / 64), blk, 0, stream>>>(
      wk, wqkvT + (size_t)HID_N * HID_N, HID_N, NKV * HD, NKV * HD);
  transpose_cast<<<dim3((NKV * HD) / 64, HID_N / 64), blk, 0, stream>>>(
      wv, wqkvT + (size_t)(HID_N + NKV * HD) * HID_N, HID_N, NKV * HD, NKV * HD);

  // fused QKV projection: [2048][4096] @ [4096][6144] -> [2048][6144]
  gemm_bf16<<<dim3(6144 / 128, S_LEN / 128), blk, 0, stream>>>(hb, wqkvT, qkv, S_LEN, 6144, HID_N);

  transpose_cast<<<dim3(HID_N / 64, HID_N / 64), blk, 0, stream>>>(wo, woT, NH * HD, HID_N, HID_N);

  rope_cast<<<(S_LEN * NH * 64) / 256, blk, 0, stream>>>(qkv, qb16, NH, 6144, NH * HD);
  rope_cast<<<(S_LEN * NKV * 64) / 256, blk, 0, stream>>>(qkv + HID_N, kb16, NKV, 6144, NKV * HD);
  transpose_cast<<<dim3((NKV * HD) / 64, S_LEN / 64), blk, 0, stream>>>(
      qkv + HID_N + NKV * HD, vT16, S_LEN, NKV * HD, 6144);

  attn_mfma<2048><<<dim3(64, NH), blk, 0, stream>>>(qb16, kb16, vT16, aob, 64);
  attn_mfma<1024><<<dim3(64, NH), blk, 0, stream>>>(qb16, kb16, vT16, aob, 0);

  gemm_bf16<<<dim3(HID_N / 128, S_LEN / 128), blk, 0, stream>>>(aob, woT, out, S_LEN, HID_N, NH * HD);
}

// Round 3
// 850.925 us; speedup vs baseline: 2.5267x; 1.1069x over previous
//
#include <hip/hip_runtime.h>
#include <math.h>

#define S_LEN 2048
#define HID_N 4096
#define NH 32
#define NKV 8
#define HD 128
#define INIT_N 128
#define RECENT_N 512
#define HEAVY_N 512
#define SCALE_QK 0.08838834764831845f

typedef __attribute__((ext_vector_type(8))) short short8;
typedef __attribute__((ext_vector_type(4))) float float4v;

__device__ __forceinline__ unsigned short f2bf(float f) {
  unsigned u = __float_as_uint(f);
  unsigned r = (u + 0x7FFFu + ((u >> 16) & 1u)) >> 16;  // RNE (inputs finite)
  return (unsigned short)r;
}

__device__ __forceinline__ float bf2f(unsigned u) { return __uint_as_float(u << 16); }

__device__ __forceinline__ unsigned fkey16(unsigned u) {
  return (u & 0x8000u) ? ((~u) & 0xFFFFu) : (u | 0x8000u);
}

__device__ __forceinline__ void gld_lds16(const unsigned short* g, unsigned short* l) {
  __builtin_amdgcn_global_load_lds(
      (const __attribute__((address_space(1))) unsigned int*)g,
      (__attribute__((address_space(3))) unsigned int*)l, 16, 0, 0);
}

// ---------------- elementwise cast fp32 -> bf16, 8 per thread ----------------
__global__ __launch_bounds__(256) void cast_bf16x8(const float* __restrict__ x,
                                                   unsigned short* __restrict__ y, int n) {
  int i = (blockIdx.x * 256 + threadIdx.x) << 3;
  if (i >= n) return;
  float4 a = *(const float4*)(x + i);
  float4 b = *(const float4*)(x + i + 4);
  union { unsigned short u[8]; short8 v; } o;
  o.u[0] = f2bf(a.x); o.u[1] = f2bf(a.y); o.u[2] = f2bf(a.z); o.u[3] = f2bf(a.w);
  o.u[4] = f2bf(b.x); o.u[5] = f2bf(b.y); o.u[6] = f2bf(b.z); o.u[7] = f2bf(b.w);
  *(short8*)(y + i) = o.v;
}

// ------------- transpose + cast: w[R][C] (row stride ldw) -> wt[C][R] bf16 ---
__global__ __launch_bounds__(256) void transpose_cast(const float* __restrict__ w,
                                                      unsigned short* __restrict__ wt,
                                                      int R, int C, int ldw) {
  __shared__ unsigned short t[64][65];
  const int c0 = blockIdx.x * 64;
  const int r0 = blockIdx.y * 64;
  const int tx = threadIdx.x & 63;
  const int ty = threadIdx.x >> 6;
#pragma unroll
  for (int i = 0; i < 16; ++i)
    t[ty + 4 * i][tx] = f2bf(w[(size_t)(r0 + ty + 4 * i) * ldw + c0 + tx]);
  __syncthreads();
#pragma unroll
  for (int i = 0; i < 16; ++i)
    wt[(size_t)(c0 + ty + 4 * i) * R + r0 + tx] = t[tx][ty + 4 * i];
}

// ---------------- bf16 MFMA GEMM (m97 pattern): C = A[M][K] @ BT[N][K]^T -----
__global__ __launch_bounds__(256) void gemm_bf16(const unsigned short* __restrict__ A,
                                                 const unsigned short* __restrict__ BT,
                                                 float* __restrict__ C,
                                                 int M, int N, int K) {
  __shared__ __align__(16) unsigned short As[128 * 32];
  __shared__ __align__(16) unsigned short Bs[128 * 32];
  const int tid = threadIdx.x;
  const int lane = tid & 63;
  const int wid = tid >> 6;
  const int m0 = blockIdx.y * 128;
  const int n0 = blockIdx.x * 128;
  const int wm = (wid & 1) * 64;
  const int wn = (wid >> 1) * 64;
  const int col = lane & 15;
  const int quad = lane >> 4;

  float4v acc[4][4] = {};

  const int crow = tid >> 2;
  const int ckc = (tid & 3) << 3;

  for (int k0 = 0; k0 < K; k0 += 32) {
#pragma unroll
    for (int i = 0; i < 2; ++i) {
      const int row = i * 64 + crow;
      unsigned short* la = &As[(i * 256 + wid * 64) << 3];
      unsigned short* lb = &Bs[(i * 256 + wid * 64) << 3];
      gld_lds16(A + (size_t)(m0 + row) * K + k0 + ckc, la);
      gld_lds16(BT + (size_t)(n0 + row) * K + k0 + ckc, lb);
    }
    __syncthreads();

    short8 af[4], bf[4];
#pragma unroll
    for (int i = 0; i < 4; ++i) {
      af[i] = *(const short8*)&As[((wm + 16 * i + col) << 5) + (quad << 3)];
      bf[i] = *(const short8*)&Bs[((wn + 16 * i + col) << 5) + (quad << 3)];
    }
#pragma unroll
    for (int i = 0; i < 4; ++i)
#pragma unroll
      for (int j = 0; j < 4; ++j)
        acc[i][j] = __builtin_amdgcn_mfma_f32_16x16x32_bf16(af[i], bf[j], acc[i][j], 0, 0, 0);
    __syncthreads();
  }

#pragma unroll
  for (int i = 0; i < 4; ++i)
#pragma unroll
    for (int j = 0; j < 4; ++j) {
      size_t base = (size_t)(m0 + wm + 16 * i + quad * 4) * N + n0 + wn + 16 * j + col;
      C[base] = acc[i][j][0];
      C[base + N] = acc[i][j][1];
      C[base + 2 * (size_t)N] = acc[i][j][2];
      C[base + 3 * (size_t)N] = acc[i][j][3];
    }
}

// ------- RoPE + cast to bf16: x[S][*] (stride ldx) -> y (stride ldy) bf16 ----
__global__ __launch_bounds__(256) void rope_cast(const float* __restrict__ x,
                                                 unsigned short* __restrict__ y,
                                                 int nheads, int ldx, int ldy) {
  int idx = blockIdx.x * 256 + threadIdx.x;
  int i = idx & 63;
  int rest = idx >> 6;
  int hh = rest % nheads;
  int s = rest / nheads;
  if (s >= S_LEN) return;
  const float* p = x + (size_t)s * ldx + hh * HD;
  unsigned short* o = y + (size_t)s * ldy + hh * HD;
  float inv = (float)(1.0 / pow(10000.0, (double)(2 * i) / 128.0));
  float ang = (float)s * inv;
  float c = cosf(ang);
  float sn = sinf(ang);
  float x1 = p[i];
  float x2 = p[i + 64];
  o[i] = f2bf(x1 * c - x2 * sn);
  o[i + 64] = f2bf(x2 * c + x1 * sn);
}

// ------------ fused heavy-hitter attention, MFMA, 16 q-rows, 8 waves ---------
// qb: bf16 [S][NH*HD] (RoPE'd), kb: bf16 [S][NKV*HD] (RoPE'd),
// vt: bf16 [NKV*HD][S] (V transposed), ao16: bf16 [S][NH*HD].
// Scores in LDS as bf16, XOR-swizzled: idx(q,k) = (q*SMAX + k) ^ ((q&7)<<3).
// 8 waves/block (512 thr): Phase A tiles stride-8, Phase B 2 rows/wave,
// Phase C 16-wide d-slice/wave. SMAX=1024 launch: radix statically dead,
// 32KB LDS; SMAX=2048: 64.5KB LDS -> 2 blocks/CU but 16 waves/CU.
template <int SMAX>
__global__ __launch_bounds__(512, 4)
void attn_mfma(const unsigned short* __restrict__ qb,
               const unsigned short* __restrict__ kb,
               const unsigned short* __restrict__ vt,
               unsigned short* __restrict__ ao16, int qbase) {
  const int qi0 = (qbase + blockIdx.x) << 4;
  const int h = blockIdx.y;
  const int g = h >> 2;
  const int tid = threadIdx.x;
  const int lane = tid & 63;
  const int wid = tid >> 6;          // 0..7
  const int col = lane & 15;
  const int quad = lane >> 4;
  const int nkm = qi0 + 16;
  const int nkm32 = (nkm + 31) & ~31;

  __shared__ __align__(16) unsigned short sc[16 * SMAX];
  __shared__ float sumv[16];

  // ---- Phase A: S = (Q K^T) * scale via MFMA, tiles stride-8, 2 deep ----
  short8 qf[4];
  {
    const unsigned short* qrow = qb + (size_t)(qi0 + col) * (NH * HD) + h * HD + (quad << 3);
#pragma unroll
    for (int dt = 0; dt < 4; ++dt) qf[dt] = *(const short8*)(qrow + dt * 32);
  }
  const int ntiles = nkm >> 4;
  int t = wid;
  for (; t + 8 < ntiles; t += 16) {
    const int k0a = t << 4;
    const int k0b = (t + 8) << 4;
    const unsigned short* kra = kb + (size_t)(k0a + col) * (NKV * HD) + g * HD + (quad << 3);
    const unsigned short* krb = kb + (size_t)(k0b + col) * (NKV * HD) + g * HD + (quad << 3);
    short8 kfa[4], kfb[4];
#pragma unroll
    for (int dt = 0; dt < 4; ++dt) kfa[dt] = *(const short8*)(kra + dt * 32);
#pragma unroll
    for (int dt = 0; dt < 4; ++dt) kfb[dt] = *(const short8*)(krb + dt * 32);
    float4v acca = {}, accb = {};
#pragma unroll
    for (int dt = 0; dt < 4; ++dt) {
      acca = __builtin_amdgcn_mfma_f32_16x16x32_bf16(qf[dt], kfa[dt], acca, 0, 0, 0);
      accb = __builtin_amdgcn_mfma_f32_16x16x32_bf16(qf[dt], kfb[dt], accb, 0, 0, 0);
    }
#pragma unroll
    for (int r = 0; r < 4; ++r) {
      int q = (quad << 2) + r;
      sc[(q * SMAX + k0a + col) ^ ((q & 7) << 3)] = f2bf(acca[r] * SCALE_QK);
      sc[(q * SMAX + k0b + col) ^ ((q & 7) << 3)] = f2bf(accb[r] * SCALE_QK);
    }
  }
  if (t < ntiles) {
    const int k0 = t << 4;
    const unsigned short* krow = kb + (size_t)(k0 + col) * (NKV * HD) + g * HD + (quad << 3);
    float4v acc = {};
#pragma unroll
    for (int dt = 0; dt < 4; ++dt) {
      short8 kf = *(const short8*)(krow + dt * 32);
      acc = __builtin_amdgcn_mfma_f32_16x16x32_bf16(qf[dt], kf, acc, 0, 0, 0);
    }
#pragma unroll
    for (int r = 0; r < 4; ++r) {
      int q = (quad << 2) + r;
      sc[(q * SMAX + k0 + col) ^ ((q & 7) << 3)] = f2bf(acc[r] * SCALE_QK);
    }
  }
  __syncthreads();

  // ---- Phase B: per-row top-k threshold + softmax (wave w owns rows 2w,2w+1) ----
  const unsigned long long lmlt = (1ull << lane) - 1ull;
#pragma unroll 1
  for (int rr = 0; rr < 2; ++rr) {
    const int r = (wid << 1) + rr;
    const int qi = qi0 + r;
    const int mhi = qi - RECENT_N;       // last middle index
    const int m = mhi - INIT_N + 1;      // middle count
    const bool need = (SMAX > 1024) && (m > HEAVY_N);
    const unsigned swz = (r & 7) << 3;
    const int rbase = r * SMAX;

    unsigned T = 0, rem = 0;
    if (need) {
      // 16-bit radix select over bf16 score keys; pads (0) never match target.
      unsigned myk[22];
#pragma unroll
      for (int j = 0; j < 11; ++j) {
        int off = (lane + (j << 6)) << 1;  // 0..1406 step 2, covers m <= 1408
        unsigned u = *(const unsigned*)&sc[(rbase + INIT_N + off) ^ swz];
        unsigned f0 = fkey16(u & 0xFFFFu);
        unsigned f1 = fkey16(u >> 16);
        myk[2 * j] = (off < m) ? f0 : 0u;
        myk[2 * j + 1] = (off + 1 < m) ? f1 : 0u;
      }
      unsigned prefix = 0, rm = HEAVY_N;
#pragma unroll 1
      for (int bit = 15; bit >= 0; --bit) {
        unsigned target = (prefix >> bit) | 1u;
        unsigned cnt = 0;
#pragma unroll
        for (int j = 0; j < 22; ++j)
          cnt += (unsigned)__popcll(__ballot((myk[j] >> bit) == target));
        if (cnt >= rm) prefix |= (1u << bit);
        else rm -= cnt;
      }
      T = prefix;
      rem = rm;
    }

    // Max over causal range only: the causal max is always in the selected set.
    float mx = -3.402823466e38f;
#pragma unroll 1
    for (int c0 = 0; c0 <= qi; c0 += 128) {
      int k2 = c0 + (lane << 1);
      unsigned u = *(const unsigned*)&sc[(rbase + k2) ^ swz];
      float s0 = bf2f(u & 0xFFFFu);
      float s1 = bf2f(u >> 16);
      if (k2 <= qi) mx = fmaxf(mx, s0);
      if (k2 + 1 <= qi) mx = fmaxf(mx, s1);
    }
#pragma unroll
    for (int off = 32; off; off >>= 1) mx = fmaxf(mx, __shfl_xor(mx, off, 64));

    float sum = 0.f;
    unsigned cum = 0;
#pragma unroll 1
    for (int c0 = 0; c0 < nkm32; c0 += 128) {
      int k2 = c0 + (lane << 1);
      int idx = (rbase + k2) ^ swz;
      unsigned u = *(const unsigned*)&sc[idx];
      bool ic0 = k2 <= qi, ic1 = (k2 + 1) <= qi;
      bool sel0, sel1;
      if (!need) {
        sel0 = ic0;
        sel1 = ic1;
      } else {
        bool mid0 = ic0 && (k2 >= INIT_N) && (k2 <= mhi);
        bool mid1 = ic1 && (k2 + 1 >= INIT_N) && (k2 + 1 <= mhi);
        unsigned f0 = fkey16(u & 0xFFFFu);
        unsigned f1 = fkey16(u >> 16);
        unsigned long long eq0 = __ballot(mid0 && (f0 == T));
        unsigned long long eq1 = __ballot(mid1 && (f1 == T));
        unsigned pre0 = cum + (unsigned)__popcll(eq0 & lmlt) + (unsigned)__popcll(eq1 & lmlt);
        unsigned pre1 = pre0 + (unsigned)((eq0 >> lane) & 1ull);
        sel0 = ic0 && (!mid0 || (f0 > T) || ((f0 == T) && (pre0 < rem)));
        sel1 = ic1 && (!mid1 || (f1 > T) || ((f1 == T) && (pre1 < rem)));
        cum += (unsigned)__popcll(eq0) + (unsigned)__popcll(eq1);
      }
      float e0 = sel0 ? __expf(bf2f(u & 0xFFFFu) - mx) : 0.f;
      float e1 = sel1 ? __expf(bf2f(u >> 16) - mx) : 0.f;
      sum += e0 + e1;
      *(unsigned*)&sc[idx] = (unsigned)f2bf(e0) | ((unsigned)f2bf(e1) << 16);
    }
#pragma unroll
    for (int off = 32; off; off >>= 1) sum += __shfl_xor(sum, off, 64);
    if (lane == 0) sumv[r] = sum;
  }
  __syncthreads();

  // ---- Phase C: O = P V via MFMA; wave w owns d-slice [16w, 16w+16) --------
  float4v a0 = {}, b0 = {};
  const int db = wid << 4;
  const unsigned short* vrow = vt + (size_t)(g * HD + db + col) * S_LEN + (quad << 3);
  const unsigned pswz = (unsigned)((col & 7) << 3);
  int k0 = 0;
  for (; k0 + 32 < nkm32; k0 += 64) {
    short8 pf0 = *(const short8*)&sc[(col * SMAX + k0 + (quad << 3)) ^ pswz];
    short8 pf1 = *(const short8*)&sc[(col * SMAX + k0 + 32 + (quad << 3)) ^ pswz];
    short8 v0 = *(const short8*)(vrow + k0);
    short8 v1 = *(const short8*)(vrow + k0 + 32);
    a0 = __builtin_amdgcn_mfma_f32_16x16x32_bf16(pf0, v0, a0, 0, 0, 0);
    b0 = __builtin_amdgcn_mfma_f32_16x16x32_bf16(pf1, v1, b0, 0, 0, 0);
  }
  if (k0 < nkm32) {
    short8 pf = *(const short8*)&sc[(col * SMAX + k0 + (quad << 3)) ^ pswz];
    short8 v0 = *(const short8*)(vrow + k0);
    a0 = __builtin_amdgcn_mfma_f32_16x16x32_bf16(pf, v0, a0, 0, 0, 0);
  }
  a0 += b0;
#pragma unroll
  for (int r = 0; r < 4; ++r) {
    int qq = (quad << 2) + r;
    float inv = 1.0f / sumv[qq];
    size_t o = (size_t)(qi0 + qq) * (NH * HD) + h * HD + db;
    ao16[o + col] = f2bf(a0[r] * inv);
  }
}

// ---------------------------------------------------------------------------
extern "C" void kernel_launch(void* const* d_in, const int* in_sizes, int n_in,
                              void* d_out, int out_size, void* d_ws, size_t ws_size,
                              hipStream_t stream) {
  const float* hidden = (const float*)d_in[0];
  const float* wq = (const float*)d_in[1];
  const float* wk = (const float*)d_in[2];
  const float* wv = (const float*)d_in[3];
  const float* wo = (const float*)d_in[4];
  float* out = (float*)d_out;

  // workspace layout (floats), 30M floats = 120 MB used:
  //  [ 0M,12M)  qkv f32 [S][6144] (q | k | v)
  //  [12M,16M)  qb16 bf16 [S][NH*HD]
  //  [16M,20M)  hb bf16 [S][HID]           -> reused as aob bf16
  //  [20M,32M)  wqkvT bf16 [6144][4096]    -> after QKV gemm reused:
  //               [20M,28M) woT bf16 [4096][4096]
  //               [28M,29M) kb16 bf16 [S][NKV*HD]
  //               [29M,30M) vT16 bf16 [NKV*HD][S]
  float* ws = (float*)d_ws;
  const size_t M1 = 1024 * 1024;
  float* qkv = ws;
  unsigned short* qb16 = (unsigned short*)(ws + 12 * M1);
  unsigned short* hb = (unsigned short*)(ws + 16 * M1);
  unsigned short* aob = hb;
  unsigned short* wqkvT = (unsigned short*)(ws + 20 * M1);
  unsigned short* woT = wqkvT;
  unsigned short* kb16 = (unsigned short*)(ws + 28 * M1);
  unsigned short* vT16 = (unsigned short*)(ws + 29 * M1);

  dim3 blk(256);
  const int NE = S_LEN * HID_N;  // 8,388,608

  cast_bf16x8<<<NE / 2048, blk, 0, stream>>>(hidden, hb, NE);
  transpose_cast<<<dim3(HID_N / 64, HID_N / 64), blk, 0, stream>>>(wq, wqkvT, HID_N, HID_N, HID_N);
  transpose_cast<<<dim3((NKV * HD) / 64, HID_N / 64), blk, 0, stream>>>(
      wk, wqkvT + (size_t)HID_N * HID_N, HID_N, NKV * HD, NKV * HD);
  transpose_cast<<<dim3((NKV * HD) / 64, HID_N / 64), blk, 0, stream>>>(
      wv, wqkvT + (size_t)(HID_N + NKV * HD) * HID_N, HID_N, NKV * HD, NKV * HD);

  // fused QKV projection: [2048][4096] @ [4096][6144] -> [2048][6144]
  gemm_bf16<<<dim3(6144 / 128, S_LEN / 128), blk, 0, stream>>>(hb, wqkvT, qkv, S_LEN, 6144, HID_N);

  transpose_cast<<<dim3(HID_N / 64, HID_N / 64), blk, 0, stream>>>(wo, woT, NH * HD, HID_N, HID_N);

  rope_cast<<<(S_LEN * NH * 64) / 256, blk, 0, stream>>>(qkv, qb16, NH, 6144, NH * HD);
  rope_cast<<<(S_LEN * NKV * 64) / 256, blk, 0, stream>>>(qkv + HID_N, kb16, NKV, 6144, NKV * HD);
  transpose_cast<<<dim3((NKV * HD) / 64, S_LEN / 64), blk, 0, stream>>>(
      qkv + HID_N + NKV * HD, vT16, S_LEN, NKV * HD, 6144);

  attn_mfma<2048><<<dim3(64, NH), dim3(512), 0, stream>>>(qb16, kb16, vT16, aob, 64);
  attn_mfma<1024><<<dim3(64, NH), dim3(512), 0, stream>>>(qb16, kb16, vT16, aob, 0);

  gemm_bf16<<<dim3(HID_N / 128, S_LEN / 128), blk, 0, stream>>>(aob, woT, out, S_LEN, HID_N, NH * HD);
}